// Round 1
// baseline (836.298 us; speedup 1.0000x reference)
//
#include <hip/hip_runtime.h>

#define GROUPS 2
#define VQ 320
#define NCOLS 640            // GROUPS * VQ
#define KDIM 768
#define BM 32                // rows per block
#define BK 16                // k-tile
#define THREADS 320          // 4 row-groups x 80 col-threads

struct VR { float v; int i; };

__global__ __launch_bounds__(THREADS, 2)
void vq_gemm_argmax_gather(const float* __restrict__ x,
                           const float* __restrict__ W,
                           const float* __restrict__ b,
                           const float* __restrict__ cb,
                           float* __restrict__ out)
{
    __shared__ float ws[BK][NCOLS];          // 40 KB, overlaid by VR red[] in epilogue
    __shared__ float xs[BK][BM];             // 2 KB, transposed x tile
    __shared__ int   kbuf[BM][GROUPS];

    const int t   = threadIdx.x;
    const int c   = t % 80;                  // col-thread: cols 4c..4c+3 (+VQ for group 1)
    const int rg  = t / 80;                  // row-group: rows 8*rg..8*rg+7
    const int row0 = blockIdx.x * BM;

    float acc[8][8];
#pragma unroll
    for (int r = 0; r < 8; ++r)
#pragma unroll
        for (int l = 0; l < 8; ++l) acc[r][l] = 0.f;

    for (int k0 = 0; k0 < KDIM; k0 += BK) {
        __syncthreads();
        // ---- stage W tile: 16 x 640 f32 = 2560 float4, coalesced ----
#pragma unroll
        for (int i = 0; i < 8; ++i) {
            int idx = t + i * THREADS;       // 0..2559
            int kr  = idx / 160;
            int c4  = idx % 160;
            float4 v = *reinterpret_cast<const float4*>(&W[(size_t)(k0 + kr) * NCOLS + c4 * 4]);
            *reinterpret_cast<float4*>(&ws[kr][c4 * 4]) = v;
        }
        // ---- stage x tile transposed: 32 rows x 16 k ----
        if (t < 128) {
            int row = t >> 2, j = t & 3;
            float4 v = *reinterpret_cast<const float4*>(&x[(size_t)(row0 + row) * KDIM + k0 + j * 4]);
            xs[j * 4 + 0][row] = v.x;
            xs[j * 4 + 1][row] = v.y;
            xs[j * 4 + 2][row] = v.z;
            xs[j * 4 + 3][row] = v.w;
        }
        __syncthreads();
        // ---- register-tiled FMA: 16 k-steps x (8 rows x 8 cols) ----
#pragma unroll
        for (int kk = 0; kk < BK; ++kk) {
            float4 xa = *reinterpret_cast<const float4*>(&xs[kk][rg * 8]);
            float4 xb = *reinterpret_cast<const float4*>(&xs[kk][rg * 8 + 4]);
            float4 w0 = *reinterpret_cast<const float4*>(&ws[kk][c * 4]);
            float4 w1 = *reinterpret_cast<const float4*>(&ws[kk][c * 4 + VQ]);
            float xr[8] = {xa.x, xa.y, xa.z, xa.w, xb.x, xb.y, xb.z, xb.w};
            float wv[8] = {w0.x, w0.y, w0.z, w0.w, w1.x, w1.y, w1.z, w1.w};
#pragma unroll
            for (int r = 0; r < 8; ++r)
#pragma unroll
                for (int l = 0; l < 8; ++l)
                    acc[r][l] = fmaf(xr[r], wv[l], acc[r][l]);
        }
    }

    __syncthreads();
    // ---- epilogue: per-row argmax per group (first-occurrence tie-break) ----
    VR* red = reinterpret_cast<VR*>(&ws[0][0]);   // [BM][GROUPS][80], 40960 B == sizeof(ws)
    float bv[8];
    {
        float4 b0 = *reinterpret_cast<const float4*>(&b[c * 4]);
        float4 b1 = *reinterpret_cast<const float4*>(&b[c * 4 + VQ]);
        bv[0] = b0.x; bv[1] = b0.y; bv[2] = b0.z; bv[3] = b0.w;
        bv[4] = b1.x; bv[5] = b1.y; bv[6] = b1.z; bv[7] = b1.w;
    }
#pragma unroll
    for (int r = 0; r < 8; ++r) {
        int row = rg * 8 + r;
        // group 0: local cols 4c..4c+3
        float bestv = acc[r][0] + bv[0]; int besti = c * 4;
#pragma unroll
        for (int l = 1; l < 4; ++l) {
            float v = acc[r][l] + bv[l];
            if (v > bestv) { bestv = v; besti = c * 4 + l; }
        }
        red[(row * 2 + 0) * 80 + c] = VR{bestv, besti};
        // group 1
        bestv = acc[r][4] + bv[4]; besti = c * 4;
#pragma unroll
        for (int l = 1; l < 4; ++l) {
            float v = acc[r][l + 4] + bv[l + 4];
            if (v > bestv) { bestv = v; besti = c * 4 + l; }
        }
        red[(row * 2 + 1) * 80 + c] = VR{bestv, besti};
    }
    __syncthreads();
    if (t < BM * GROUPS) {
        int row = t >> 1, g = t & 1;
        const VR* rr = &red[(row * 2 + g) * 80];
        float bestv = rr[0].v; int besti = rr[0].i;
        for (int i = 1; i < 80; ++i) {        // ascending i == ascending col -> first-occurrence
            float v = rr[i].v;
            if (v > bestv) { bestv = v; besti = rr[i].i; }
        }
        kbuf[row][g] = besti;
    }
    __syncthreads();
    // ---- gather codebook rows -> out, coalesced float4 ----
    const float4* cb4  = reinterpret_cast<const float4*>(cb);
    float4*       out4 = reinterpret_cast<float4*>(out);
    for (int e = t; e < BM * GROUPS * 32; e += THREADS) {
        int pair = e >> 5, q = e & 31;        // 32 float4 per codebook row (128 f32)
        int row = pair >> 1, g = pair & 1;
        int k = kbuf[row][g];
        out4[(size_t)(row0 + row) * 64 + g * 32 + q] = cb4[(size_t)k * 32 + q];
    }
}

extern "C" void kernel_launch(void* const* d_in, const int* in_sizes, int n_in,
                              void* d_out, int out_size, void* d_ws, size_t ws_size,
                              hipStream_t stream) {
    const float* x  = (const float*)d_in[0];   // [8*4096, 768]
    const float* W  = (const float*)d_in[1];   // [768, 640]
    const float* b  = (const float*)d_in[2];   // [640]
    const float* cb = (const float*)d_in[3];   // [320, 128]
    float* out = (float*)d_out;                // [8*4096, 256]

    const int M = in_sizes[0] / KDIM;          // 32768
    dim3 grid(M / BM);
    dim3 block(THREADS);
    vq_gemm_argmax_gather<<<grid, block, 0, stream>>>(x, W, b, cb, out);
}